// Round 22
// baseline (185.980 us; speedup 1.0000x reference)
//
#include <hip/hip_runtime.h>

// Problem constants
#define NB      32      // batch
#define INF     128     // in_flt
#define NPIX    64      // N
#define TSP     16      // t
#define OUTF    32      // out_flt
#define FF      16      // intermediate features
#define D_IN    768     // 3*t*t
#define D_OUT   8192    // out_flt*t*t
#define NCOL    (D_OUT*FF)   // 131072
#define OUTCH   160     // in_flt + out_flt
#define BSTRIDE 655360  // 160*64*64 floats per batch in d_out
#define KCH     4       // k-chunks
#define KROWS   192     // rows per k-chunk
#define NBNCOL  ((size_t)NB*NCOL)

typedef __attribute__((address_space(1))) const void glb_cv;
typedef __attribute__((address_space(3))) void lds_v;

// K1: fused strided conv (128ch,4x4,stride4 -> 3ch) + x->out concat copy.
__global__ __launch_bounds__(256) void k1_conv_copy(
    const float* __restrict__ x, const float* __restrict__ wc,
    float* __restrict__ out, float* __restrict__ At)
{
    __shared__ float sW[3*128*16];     // 24 KB
    __shared__ float sP[16][16][3];
    const int b   = blockIdx.x >> 4;
    const int oi  = blockIdx.x & 15;
    const int tid = threadIdx.x;
    for (int idx = tid; idx < 6144; idx += 256) sW[idx] = wc[idx];
    __syncthreads();
    const int icg = tid >> 4;
    const int j   = tid & 15;
    float a0 = 0.f, a1 = 0.f, a2 = 0.f;
    for (int ic8 = 0; ic8 < 8; ++ic8) {
        const int ic = icg*8 + ic8;
        #pragma unroll
        for (int ki = 0; ki < 4; ++ki) {
            const int row = 4*oi + ki;
            const float4 xv = *(const float4*)(x + ((size_t)(b*INF+ic)*NPIX + row)*NPIX + 4*j);
            *(float4*)(out + ((size_t)(b*OUTCH+ic)*NPIX + row)*NPIX + 4*j) = xv;
            const float* w0 = sW + ((0*INF+ic)*4 + ki)*4;
            const float* w1 = sW + ((1*INF+ic)*4 + ki)*4;
            const float* w2 = sW + ((2*INF+ic)*4 + ki)*4;
            a0 += xv.x*w0[0] + xv.y*w0[1] + xv.z*w0[2] + xv.w*w0[3];
            a1 += xv.x*w1[0] + xv.y*w1[1] + xv.z*w1[2] + xv.w*w1[3];
            a2 += xv.x*w2[0] + xv.y*w2[1] + xv.z*w2[2] + xv.w*w2[3];
        }
    }
    sP[icg][j][0] = a0; sP[icg][j][1] = a1; sP[icg][j][2] = a2;
    __syncthreads();
    if (tid < 48) {
        const int c3 = tid >> 4, jj = tid & 15;
        float s = 0.f;
        #pragma unroll
        for (int g = 0; g < 16; ++g) s += sP[g][jj][c3];
        At[(c3*256 + oi*16 + jj)*32 + b] = s;
    }
}

// K2 v19: R=1 via LDS sharing + __builtin_amdgcn_global_load_lds staging.
// Ledger reconciliation: v14(126us) == its HBM demand exactly (B_t=16 ->
// 2x T redundancy, 870MB @ ~6.9TB/s = 126) -> BW-bound on redundant bytes.
// Demand is structurally (32/B_t)*402MB; only LDS sharing gives R=1.
// v17 tried (536MB, floor 85) but ran 136: register round-trip staging
// (global->VGPR->vmcnt->ds_write) ate the gain. v19 stages DIRECT
// HBM->LDS (global_load_lds width=16; compiler never auto-emits, +35%
// vs reg-staging at this shape per guide m151). 2-phase template:
// STAGE(buf^1) -> consume(buf) -> one __syncthreads()/tile (its vmcnt(0)
// drain lands the staged tile). acc[8][4]=32 VGPR -> ~65 total ->
// 3 blocks/CU = 6 w/SIMD. Demand 469MB -> floor ~75us.
__global__ __launch_bounds__(512, 6) void k2_gemm(
    const float* __restrict__ At, const float* __restrict__ Tm,
    float* __restrict__ Mp)
{
    __shared__ float sT[2][8*512];     // 2 x 16 KB tiles
    const int tid  = threadIdx.x;
    const int kc   = blockIdx.x >> 8;  // 0..3   (SGPR)
    const int cc   = blockIdx.x & 255; // 0..255 (SGPR)
    const int k0g  = kc * KROWS;
    const int wid  = __builtin_amdgcn_readfirstlane(tid >> 6);  // wave 0..7
    const int lane = tid & 63;
    const int bg   = __builtin_amdgcn_readfirstlane(tid >> 7);  // 0..3
    const int ct   = tid & 127;

    const float* tbase = Tm + (size_t)k0g*NCOL + cc*512;
    const float* ap    = At + k0g*32 + bg*8;   // uniform -> s_load path

    float acc[8][4];
    #pragma unroll
    for (int i = 0; i < 8; ++i)
        #pragma unroll
        for (int j = 0; j < 4; ++j) acc[i][j] = 0.f;

    // Stage 8 rows x 512 cols (16 KB) of T into sT[buf]: 16 wave-instrs,
    // 2 per wave. idx = wid*2+i -> row=idx>>1, half=idx&1. LDS dst is
    // wave-uniform base (idx wave-uniform); global src per-lane, 1 KB
    // contiguous per wave-instr (coalesced).
#define STAGE(BUF, TROW0) { \
    _Pragma("unroll") \
    for (int i = 0; i < 2; ++i) { \
        const int idx = wid*2 + i; \
        const float* g = tbase + (size_t)((TROW0) + (idx>>1))*NCOL \
                               + (idx&1)*256 + lane*4; \
        __builtin_amdgcn_global_load_lds((glb_cv*)g, \
            (lds_v*)&sT[BUF][idx*256], 16, 0, 0); \
    } }

    // prologue: stage tile 0
    STAGE(0, 0)
    __syncthreads();   // vmcnt(0) drain: tile 0 landed

    const int NT = KROWS/8;            // 24 tiles
    for (int t = 0; t < NT; ++t) {
        const int cur = t & 1;
        if (t + 1 < NT) STAGE(cur ^ 1, (t+1)*8)   // in flight during consume
        #pragma unroll
        for (int r = 0; r < 8; ++r) {
            const float4 tv = *(const float4*)&sT[cur][r*512 + ct*4];
            const float* av = ap + (t*8 + r)*32;   // uniform (SGPR) addr
            const float4 aL = *(const float4*)(av);
            const float4 aH = *(const float4*)(av + 4);
            acc[0][0]+=aL.x*tv.x; acc[0][1]+=aL.x*tv.y; acc[0][2]+=aL.x*tv.z; acc[0][3]+=aL.x*tv.w;
            acc[1][0]+=aL.y*tv.x; acc[1][1]+=aL.y*tv.y; acc[1][2]+=aL.y*tv.z; acc[1][3]+=aL.y*tv.w;
            acc[2][0]+=aL.z*tv.x; acc[2][1]+=aL.z*tv.y; acc[2][2]+=aL.z*tv.z; acc[2][3]+=aL.z*tv.w;
            acc[3][0]+=aL.w*tv.x; acc[3][1]+=aL.w*tv.y; acc[3][2]+=aL.w*tv.z; acc[3][3]+=aL.w*tv.w;
            acc[4][0]+=aH.x*tv.x; acc[4][1]+=aH.x*tv.y; acc[4][2]+=aH.x*tv.z; acc[4][3]+=aH.x*tv.w;
            acc[5][0]+=aH.y*tv.x; acc[5][1]+=aH.y*tv.y; acc[5][2]+=aH.y*tv.z; acc[5][3]+=aH.y*tv.w;
            acc[6][0]+=aH.z*tv.x; acc[6][1]+=aH.z*tv.y; acc[6][2]+=aH.z*tv.z; acc[6][3]+=aH.z*tv.w;
            acc[7][0]+=aH.w*tv.x; acc[7][1]+=aH.w*tv.y; acc[7][2]+=aH.w*tv.z; acc[7][3]+=aH.w*tv.w;
        }
        __syncthreads();   // drains vmcnt (next tile ready) + guards reuse
    }
#undef STAGE

    float* mp = Mp + (size_t)kc*NBNCOL + (size_t)(bg*8)*NCOL + cc*512 + ct*4;
    #pragma unroll
    for (int bb = 0; bb < 8; ++bb)
        *(float4*)(mp + (size_t)bb*NCOL) =
            make_float4(acc[bb][0], acc[bb][1], acc[bb][2], acc[bb][3]);
}

// K3: out[j,d] = sum_i exp(-sum_f |M[i,d,f]-M[j,d,f]|) - 1.
// Merges the 4 k-chunk partials while loading into LDS.
__global__ __launch_bounds__(256) void k3_pairs(
    const float* __restrict__ Mp, float* __restrict__ outS)
{
    extern __shared__ float sM[];      // 32*32*17 floats
    const int tid = threadIdx.x;
    const int dd0 = blockIdx.x * 32;
    for (int idx = tid; idx < 32*32*16; idx += 256) {
        const int i = idx >> 9, rem = idx & 511, d = rem >> 4, f = rem & 15;
        const size_t off = (size_t)i*NCOL + (size_t)dd0*16 + rem;
        sM[(i*32 + d)*17 + f] = (Mp[off] + Mp[off + NBNCOL])
                              + (Mp[off + 2*NBNCOL] + Mp[off + 3*NBNCOL]);
    }
    __syncthreads();
    const int j = tid >> 3;
    for (int q = 0; q < 4; ++q) {
        const int d = (tid & 7) + q*8;
        float mj[16];
        const float* pj = sM + (j*32 + d)*17;
        #pragma unroll
        for (int f = 0; f < 16; ++f) mj[f] = pj[f];
        float acc = 0.f;
        for (int i = 0; i < 32; ++i) {
            const float* pi = sM + (i*32 + d)*17;
            float dist = 0.f;
            #pragma unroll
            for (int f = 0; f < 16; ++f) dist += fabsf(pi[f] - mj[f]);
            acc += __expf(-dist);
        }
        outS[(size_t)j*D_OUT + dd0 + d] = acc - 1.0f;
    }
}

// K4: ConvTranspose2d, stride==kernel -> no overlap.
__global__ __launch_bounds__(256) void k4_deconv(
    const float* __restrict__ outS, const float* __restrict__ wd,
    float* __restrict__ out)
{
    __shared__ float sO[32*256];
    __shared__ float sWd[32*16];
    const int b   = blockIdx.x >> 5;
    const int oc  = blockIdx.x & 31;
    const int tid = threadIdx.x;
    for (int idx = tid; idx < 8192; idx += 256) sO[idx] = outS[(size_t)b*D_OUT + idx];
    for (int idx = tid; idx < 512; idx += 256) {
        const int ic = idx >> 4, r = idx & 15;
        sWd[idx] = wd[((ic*32 + oc) << 4) + r];
    }
    __syncthreads();
    float* ob = out + (size_t)b*BSTRIDE + (size_t)(128 + oc)*4096;
    for (int s = 0; s < 16; ++s) {
        const int p  = tid + (s << 8);
        const int i  = p >> 6, jc = p & 63;
        const int si = i >> 2, ki = i & 3, sj = jc >> 2, kj = jc & 3;
        float acc = 0.f;
        #pragma unroll
        for (int ic = 0; ic < 32; ++ic)
            acc += sO[ic*256 + si*16 + sj] * sWd[ic*16 + ki*4 + kj];
        ob[p] = acc;
    }
}

extern "C" void kernel_launch(void* const* d_in, const int* in_sizes, int n_in,
                              void* d_out, int out_size, void* d_ws, size_t ws_size,
                              hipStream_t stream) {
    const float* x  = (const float*)d_in[0];
    const float* wc = (const float*)d_in[1];
    const float* Tm = (const float*)d_in[2];
    const float* wd = (const float*)d_in[3];
    float* out  = (float*)d_out;
    float* At   = (float*)d_ws;                        // 96 KB @ 0
    float* Mp   = (float*)((char*)d_ws + (1 << 20));   // 67 MB @ 1 MB
    float* outS = (float*)((char*)d_ws + (72 << 20));  // 1 MB @ 72 MB

    k1_conv_copy<<<NB*TSP, 256, 0, stream>>>(x, wc, out, At);                   // 512 blocks
    k2_gemm    <<<KCH*256, 512, 0, stream>>>(At, Tm, Mp);                       // 1024 blocks
    k3_pairs   <<<D_OUT/32, 256, 32*32*17*sizeof(float), stream>>>(Mp, outS);   // 256 blocks
    k4_deconv  <<<NB*OUTF, 256, 0, stream>>>(outS, wd, out);                    // 1024 blocks
}

// Round 23
// 173.915 us; speedup vs baseline: 1.0694x; 1.0694x over previous
//
#include <hip/hip_runtime.h>

// Problem constants
#define NB      32      // batch
#define INF     128     // in_flt
#define NPIX    64      // N
#define TSP     16      // t
#define OUTF    32      // out_flt
#define FF      16      // intermediate features
#define D_IN    768     // 3*t*t
#define D_OUT   8192    // out_flt*t*t
#define NCOL    (D_OUT*FF)   // 131072
#define OUTCH   160     // in_flt + out_flt
#define BSTRIDE 655360  // 160*64*64 floats per batch in d_out
#define KCH     3       // k-chunks (768 blocks = exactly 3 blocks/CU)
#define KROWS   256     // rows per k-chunk
#define NT      32      // tiles per block (KROWS/8)
#define NBNCOL  ((size_t)NB*NCOL)

typedef __attribute__((address_space(1))) const void glb_cv;
typedef __attribute__((address_space(3))) void lds_v;

// K1: fused strided conv (128ch,4x4,stride4 -> 3ch) + x->out concat copy.
__global__ __launch_bounds__(256) void k1_conv_copy(
    const float* __restrict__ x, const float* __restrict__ wc,
    float* __restrict__ out, float* __restrict__ At)
{
    __shared__ float sW[3*128*16];     // 24 KB
    __shared__ float sP[16][16][3];
    const int b   = blockIdx.x >> 4;
    const int oi  = blockIdx.x & 15;
    const int tid = threadIdx.x;
    for (int idx = tid; idx < 6144; idx += 256) sW[idx] = wc[idx];
    __syncthreads();
    const int icg = tid >> 4;
    const int j   = tid & 15;
    float a0 = 0.f, a1 = 0.f, a2 = 0.f;
    for (int ic8 = 0; ic8 < 8; ++ic8) {
        const int ic = icg*8 + ic8;
        #pragma unroll
        for (int ki = 0; ki < 4; ++ki) {
            const int row = 4*oi + ki;
            const float4 xv = *(const float4*)(x + ((size_t)(b*INF+ic)*NPIX + row)*NPIX + 4*j);
            *(float4*)(out + ((size_t)(b*OUTCH+ic)*NPIX + row)*NPIX + 4*j) = xv;
            const float* w0 = sW + ((0*INF+ic)*4 + ki)*4;
            const float* w1 = sW + ((1*INF+ic)*4 + ki)*4;
            const float* w2 = sW + ((2*INF+ic)*4 + ki)*4;
            a0 += xv.x*w0[0] + xv.y*w0[1] + xv.z*w0[2] + xv.w*w0[3];
            a1 += xv.x*w1[0] + xv.y*w1[1] + xv.z*w1[2] + xv.w*w1[3];
            a2 += xv.x*w2[0] + xv.y*w2[1] + xv.z*w2[2] + xv.w*w2[3];
        }
    }
    sP[icg][j][0] = a0; sP[icg][j][1] = a1; sP[icg][j][2] = a2;
    __syncthreads();
    if (tid < 48) {
        const int c3 = tid >> 4, jj = tid & 15;
        float s = 0.f;
        #pragma unroll
        for (int g = 0; g < 16; ++g) s += sP[g][jj][c3];
        At[(c3*256 + oi*16 + jj)*32 + b] = s;
    }
}

// K2 v20: R=1 LDS sharing + global_load_lds + COUNTED-vmcnt 3-buffer
// pipeline (T3/T4). v19 diagnosis: the per-tile __syncthreads vmcnt(0)
// drain serialized tile boundaries on straggler loads (186us despite DMA
// staging). v20: per wave 2 loads/tile; iter t issues STAGE(t+2), consumes
// tile t, then waits vmcnt(2) - retires ONLY tile t+1's loads, leaves
// t+2's in flight - then RAW s_barrier (no drain). Each tile's loads get
// ~2 consume phases (>>900cyc HBM latency) to land. 3 buffers kill the
// WAR hazard. sched_barrier(0) fences inline-asm waits (guide rule #18).
// KCH=3 -> 768 blocks = exactly 3 blocks/CU (48KB LDS), 6 waves/SIMD.
// Demand 402+50 MB -> floor ~72us.
__global__ __launch_bounds__(512, 6) void k2_gemm(
    const float* __restrict__ At, const float* __restrict__ Tm,
    float* __restrict__ Mp)
{
    __shared__ float sT[3][8*512];     // 3 x 16 KB tiles
    const int tid  = threadIdx.x;
    const int kc   = blockIdx.x >> 8;  // 0..2   (SGPR)
    const int cc   = blockIdx.x & 255; // 0..255 (SGPR)
    const int k0g  = kc * KROWS;
    const int wid  = __builtin_amdgcn_readfirstlane(tid >> 6);  // wave 0..7
    const int lane = tid & 63;
    const int bg   = __builtin_amdgcn_readfirstlane(tid >> 7);  // 0..3
    const int ct   = tid & 127;

    const float* tbase = Tm + (size_t)k0g*NCOL + cc*512;
    const float* ap    = At + k0g*32 + bg*8;   // uniform -> s_load path

    float acc[8][4];
    #pragma unroll
    for (int i = 0; i < 8; ++i)
        #pragma unroll
        for (int j = 0; j < 4; ++j) acc[i][j] = 0.f;

    // Stage 8 rows x 512 cols (16 KB): 16 wave-instrs, 2 per wave.
    // idx = wid*2+i -> row=idx>>1, half=idx&1; LDS dst wave-uniform base,
    // global src per-lane 1 KB contiguous. Layout verified in v19 (passed).
#define STAGE(BUF, TROW0) { \
    _Pragma("unroll") \
    for (int i = 0; i < 2; ++i) { \
        const int idx = wid*2 + i; \
        const float* g = tbase + (size_t)((TROW0) + (idx>>1))*NCOL \
                               + (idx&1)*256 + lane*4; \
        __builtin_amdgcn_global_load_lds((glb_cv*)g, \
            (lds_v*)&sT[BUF][idx*256], 16, 0, 0); \
    } \
    __builtin_amdgcn_sched_barrier(0); }

    // prologue: stage tiles 0,1; wait tile 0 (tile 1 stays in flight)
    STAGE(0, 0)
    STAGE(1, 8)
    asm volatile("s_waitcnt vmcnt(2)" ::: "memory");
    __builtin_amdgcn_sched_barrier(0);
    __builtin_amdgcn_s_barrier();
    __builtin_amdgcn_sched_barrier(0);

    for (int t = 0; t < NT; ++t) {
        const int cur = t % 3;
        if (t + 2 < NT) STAGE((t+2) % 3, (t+2)*8)   // deep prefetch
        #pragma unroll
        for (int r = 0; r < 8; ++r) {
            const float4 tv = *(const float4*)&sT[cur][r*512 + ct*4];
            const float* av = ap + (t*8 + r)*32;    // uniform (SGPR) addr
            const float4 aL = *(const float4*)(av);
            const float4 aH = *(const float4*)(av + 4);
            acc[0][0]+=aL.x*tv.x; acc[0][1]+=aL.x*tv.y; acc[0][2]+=aL.x*tv.z; acc[0][3]+=aL.x*tv.w;
            acc[1][0]+=aL.y*tv.x; acc[1][1]+=aL.y*tv.y; acc[1][2]+=aL.y*tv.z; acc[1][3]+=aL.y*tv.w;
            acc[2][0]+=aL.z*tv.x; acc[2][1]+=aL.z*tv.y; acc[2][2]+=aL.z*tv.z; acc[2][3]+=aL.z*tv.w;
            acc[3][0]+=aL.w*tv.x; acc[3][1]+=aL.w*tv.y; acc[3][2]+=aL.w*tv.z; acc[3][3]+=aL.w*tv.w;
            acc[4][0]+=aH.x*tv.x; acc[4][1]+=aH.x*tv.y; acc[4][2]+=aH.x*tv.z; acc[4][3]+=aH.x*tv.w;
            acc[5][0]+=aH.y*tv.x; acc[5][1]+=aH.y*tv.y; acc[5][2]+=aH.y*tv.z; acc[5][3]+=aH.y*tv.w;
            acc[6][0]+=aH.z*tv.x; acc[6][1]+=aH.z*tv.y; acc[6][2]+=aH.z*tv.z; acc[6][3]+=aH.z*tv.w;
            acc[7][0]+=aH.w*tv.x; acc[7][1]+=aH.w*tv.y; acc[7][2]+=aH.w*tv.z; acc[7][3]+=aH.w*tv.w;
        }
        // counted wait: retire tile t+1's loads only; t+2's stay in flight
        if (t + 2 < NT) {
            asm volatile("s_waitcnt vmcnt(2)" ::: "memory");
        } else if (t + 1 < NT) {
            asm volatile("s_waitcnt vmcnt(0)" ::: "memory");
        }
        if (t + 1 < NT) {
            __builtin_amdgcn_sched_barrier(0);
            __builtin_amdgcn_s_barrier();      // RAW barrier: no drain
            __builtin_amdgcn_sched_barrier(0);
        }
    }
#undef STAGE

    float* mp = Mp + (size_t)kc*NBNCOL + (size_t)(bg*8)*NCOL + cc*512 + ct*4;
    #pragma unroll
    for (int bb = 0; bb < 8; ++bb)
        *(float4*)(mp + (size_t)bb*NCOL) =
            make_float4(acc[bb][0], acc[bb][1], acc[bb][2], acc[bb][3]);
}

// K3: out[j,d] = sum_i exp(-sum_f |M[i,d,f]-M[j,d,f]|) - 1.
// Merges the 3 k-chunk partials while loading into LDS.
__global__ __launch_bounds__(256) void k3_pairs(
    const float* __restrict__ Mp, float* __restrict__ outS)
{
    extern __shared__ float sM[];      // 32*32*17 floats
    const int tid = threadIdx.x;
    const int dd0 = blockIdx.x * 32;
    for (int idx = tid; idx < 32*32*16; idx += 256) {
        const int i = idx >> 9, rem = idx & 511, d = rem >> 4, f = rem & 15;
        const size_t off = (size_t)i*NCOL + (size_t)dd0*16 + rem;
        sM[(i*32 + d)*17 + f] = Mp[off] + Mp[off + NBNCOL] + Mp[off + 2*NBNCOL];
    }
    __syncthreads();
    const int j = tid >> 3;
    for (int q = 0; q < 4; ++q) {
        const int d = (tid & 7) + q*8;
        float mj[16];
        const float* pj = sM + (j*32 + d)*17;
        #pragma unroll
        for (int f = 0; f < 16; ++f) mj[f] = pj[f];
        float acc = 0.f;
        for (int i = 0; i < 32; ++i) {
            const float* pi = sM + (i*32 + d)*17;
            float dist = 0.f;
            #pragma unroll
            for (int f = 0; f < 16; ++f) dist += fabsf(pi[f] - mj[f]);
            acc += __expf(-dist);
        }
        outS[(size_t)j*D_OUT + dd0 + d] = acc - 1.0f;
    }
}

// K4: ConvTranspose2d, stride==kernel -> no overlap.
__global__ __launch_bounds__(256) void k4_deconv(
    const float* __restrict__ outS, const float* __restrict__ wd,
    float* __restrict__ out)
{
    __shared__ float sO[32*256];
    __shared__ float sWd[32*16];
    const int b   = blockIdx.x >> 5;
    const int oc  = blockIdx.x & 31;
    const int tid = threadIdx.x;
    for (int idx = tid; idx < 8192; idx += 256) sO[idx] = outS[(size_t)b*D_OUT + idx];
    for (int idx = tid; idx < 512; idx += 256) {
        const int ic = idx >> 4, r = idx & 15;
        sWd[idx] = wd[((ic*32 + oc) << 4) + r];
    }
    __syncthreads();
    float* ob = out + (size_t)b*BSTRIDE + (size_t)(128 + oc)*4096;
    for (int s = 0; s < 16; ++s) {
        const int p  = tid + (s << 8);
        const int i  = p >> 6, jc = p & 63;
        const int si = i >> 2, ki = i & 3, sj = jc >> 2, kj = jc & 3;
        float acc = 0.f;
        #pragma unroll
        for (int ic = 0; ic < 32; ++ic)
            acc += sO[ic*256 + si*16 + sj] * sWd[ic*16 + ki*4 + kj];
        ob[p] = acc;
    }
}

extern "C" void kernel_launch(void* const* d_in, const int* in_sizes, int n_in,
                              void* d_out, int out_size, void* d_ws, size_t ws_size,
                              hipStream_t stream) {
    const float* x  = (const float*)d_in[0];
    const float* wc = (const float*)d_in[1];
    const float* Tm = (const float*)d_in[2];
    const float* wd = (const float*)d_in[3];
    float* out  = (float*)d_out;
    float* At   = (float*)d_ws;                        // 96 KB @ 0
    float* Mp   = (float*)((char*)d_ws + (1 << 20));   // 50 MB @ 1 MB
    float* outS = (float*)((char*)d_ws + (72 << 20));  // 1 MB @ 72 MB

    k1_conv_copy<<<NB*TSP, 256, 0, stream>>>(x, wc, out, At);                   // 512 blocks
    k2_gemm    <<<KCH*256, 512, 0, stream>>>(At, Tm, Mp);                       // 768 blocks
    k3_pairs   <<<D_OUT/32, 256, 32*32*17*sizeof(float), stream>>>(Mp, outS);   // 256 blocks
    k4_deconv  <<<NB*OUTF, 256, 0, stream>>>(outS, wd, out);                    // 1024 blocks
}

// Round 24
// 152.608 us; speedup vs baseline: 1.2187x; 1.1396x over previous
//
#include <hip/hip_runtime.h>

// Problem constants
#define NB      32
#define INF     128
#define NPIX    64
#define TSP     16
#define OUTF    32
#define FF      16
#define D_IN    768
#define D_OUT   8192
#define NCOL    (D_OUT*FF)   // 131072
#define OUTCH   160
#define BSTRIDE 655360
#define NKS     24           // K-steps of 32 (768/32)
#define ALO     24576        // Af lo-part offset (ushorts)

typedef __attribute__((ext_vector_type(8))) short short8v;  // 8 bf16 (guide §3)
typedef __attribute__((ext_vector_type(4))) float f32x4;

static __device__ __forceinline__ ushort f2bf(float f) {
    union { float f; unsigned u; } v; v.f = f;
    return (ushort)((v.u + 0x7FFF + ((v.u >> 16) & 1)) >> 16);   // RNE
}
static __device__ __forceinline__ float bf2f(ushort h) {
    union { unsigned u; float f; } v; v.u = ((unsigned)h) << 16; return v.f;
}

// K1: fused strided conv + x->out copy. Emits A as SPLIT-bf16 MFMA
// A-fragments: Af[part][kblk(24)][bt(2)][lane(64)][j(8)] ushorts, where
// lane = ((k&31)>>3)*16 + (b&15), j = k&7 (A-operand layout of
// mfma_f32_16x16x32_bf16: row=lane&15, k=(lane>>4)*8+j).
__global__ __launch_bounds__(256) void k1_conv_copy(
    const float* __restrict__ x, const float* __restrict__ wc,
    float* __restrict__ out, ushort* __restrict__ Af)
{
    __shared__ float sW[3*128*16];
    __shared__ float sP[16][16][3];
    const int b   = blockIdx.x >> 4;
    const int oi  = blockIdx.x & 15;
    const int tid = threadIdx.x;
    for (int idx = tid; idx < 6144; idx += 256) sW[idx] = wc[idx];
    __syncthreads();
    const int icg = tid >> 4;
    const int j   = tid & 15;
    float a0 = 0.f, a1 = 0.f, a2 = 0.f;
    for (int ic8 = 0; ic8 < 8; ++ic8) {
        const int ic = icg*8 + ic8;
        #pragma unroll
        for (int ki = 0; ki < 4; ++ki) {
            const int row = 4*oi + ki;
            const float4 xv = *(const float4*)(x + ((size_t)(b*INF+ic)*NPIX + row)*NPIX + 4*j);
            *(float4*)(out + ((size_t)(b*OUTCH+ic)*NPIX + row)*NPIX + 4*j) = xv;
            const float* w0 = sW + ((0*INF+ic)*4 + ki)*4;
            const float* w1 = sW + ((1*INF+ic)*4 + ki)*4;
            const float* w2 = sW + ((2*INF+ic)*4 + ki)*4;
            a0 += xv.x*w0[0] + xv.y*w0[1] + xv.z*w0[2] + xv.w*w0[3];
            a1 += xv.x*w1[0] + xv.y*w1[1] + xv.z*w1[2] + xv.w*w1[3];
            a2 += xv.x*w2[0] + xv.y*w2[1] + xv.z*w2[2] + xv.w*w2[3];
        }
    }
    sP[icg][j][0] = a0; sP[icg][j][1] = a1; sP[icg][j][2] = a2;
    __syncthreads();
    if (tid < 48) {
        const int c3 = tid >> 4, jj = tid & 15;
        float s = 0.f;
        #pragma unroll
        for (int g = 0; g < 16; ++g) s += sP[g][jj][c3];
        const int k  = c3*256 + oi*16 + jj;
        const ushort hi = f2bf(s);
        const ushort lo = f2bf(s - bf2f(hi));
        const int fa = (k>>5)*1024 + (b>>4)*512 + ((((k>>3)&3)<<4) + (b&15))*8 + (k&7);
        Af[fa] = hi; Af[ALO + fa] = lo;
    }
}

// K2 v21: SPLIT-bf16 MFMA. R23 insight: all 9 fp32 variants pinned at
// k2~125us == 41us fmac / ~45% VALUBusy (v20 halved HBM bytes, time flat
// -> VALU-issue wall, not BW). v21 moves the inner product to the matrix
// pipe: M ~= AhiBhi + AhiBlo + AloBhi (bf16 splits, fp32 accum; rel err
// ~1e-5 -> absmax unchanged). Block 256 cols x 32 b, full K in acc
// (4 x f32x4); staging: fp32 global -> split cvt -> ds_write b32 pairs
// directly in B-frag layout (pad 520/ct); consume = ds_read_b128 + 12
// MFMA per step. A-loads issued BEFORE T-loads (in-order vmcnt retire).
__global__ __launch_bounds__(512, 4) void k2_gemm(
    const ushort* __restrict__ Af, const float* __restrict__ Tm,
    float* __restrict__ Mp)
{
    __shared__ unsigned sBu[2*8320];   // [buf][part(4160)][ct*260+fl*4+jp], 65KB
    const int tid  = threadIdx.x;
    const int lane = tid & 63;
    const int wid  = __builtin_amdgcn_readfirstlane(tid >> 6);  // 0..7
    const int bt   = wid & 1;          // batch-tile
    const int q4   = (wid >> 1) * 4;   // first col-tile of this wave
    const int colbase = blockIdx.x * 256;
    const int cgrp = tid & 31;         // col-group: cols cgrp*8..+7
    const int kk2  = (tid >> 5) * 2;   // k-pair within 32-row tile

    f32x4 acc0 = {0,0,0,0}, acc1 = {0,0,0,0}, acc2 = {0,0,0,0}, acc3 = {0,0,0,0};

    const int jp = (kk2 & 7) >> 1;
    // cvt+write one 32-row tile (held in g0..g3) into buffer nb
#define CVT_WRITE(NB_, G0,G1,G2,G3) { \
    unsigned* dH = sBu + (NB_)*8320; \
    unsigned* dL = dH + 4160; \
    const float e0[8] = {G0.x,G0.y,G0.z,G0.w,G1.x,G1.y,G1.z,G1.w}; \
    const float e1[8] = {G2.x,G2.y,G2.z,G2.w,G3.x,G3.y,G3.z,G3.w}; \
    _Pragma("unroll") \
    for (int c = 0; c < 8; ++c) { \
        const int C  = cgrp*8 + c; \
        const int o  = (C>>4)*260 + ((((kk2>>3)&3)<<4) + (C&15))*4 + jp; \
        const ushort h0 = f2bf(e0[c]), h1 = f2bf(e1[c]); \
        dH[o] = (unsigned)h0 | ((unsigned)h1 << 16); \
        const ushort l0 = f2bf(e0[c] - bf2f(h0)), l1 = f2bf(e1[c] - bf2f(h1)); \
        dL[o] = (unsigned)l0 | ((unsigned)l1 << 16); \
    } }

    // prologue: stage tile 0
    {
        const float* r0 = Tm + (size_t)kk2*NCOL + colbase + cgrp*8;
        const float4 g0 = *(const float4*)(r0);
        const float4 g1 = *(const float4*)(r0 + 4);
        const float4 g2 = *(const float4*)(r0 + NCOL);
        const float4 g3 = *(const float4*)(r0 + NCOL + 4);
        CVT_WRITE(0, g0, g1, g2, g3)
    }
    __syncthreads();

    for (int t = 0; t < NKS; ++t) {
        const int cur = t & 1;
        // A fragments first (in-order vmcnt: these retire before T loads)
        const short8v aHi = *(const short8v*)(Af + t*1024 + bt*512 + lane*8);
        const short8v aLo = *(const short8v*)(Af + ALO + t*1024 + bt*512 + lane*8);
        // next tile's T loads (stay in flight during consume)
        float4 g0, g1, g2, g3;
        const bool more = (t + 1 < NKS);
        if (more) {
            const float* r0 = Tm + (size_t)((t+1)*32 + kk2)*NCOL + colbase + cgrp*8;
            g0 = *(const float4*)(r0);
            g1 = *(const float4*)(r0 + 4);
            g2 = *(const float4*)(r0 + NCOL);
            g3 = *(const float4*)(r0 + NCOL + 4);
        }
        // consume tile t: 4 col-tiles x (hi*hi + hi*lo + lo*hi)
        const ushort* bbase = (const ushort*)sBu + cur*16640 + lane*8;
        {
            const short8v bHi0 = *(const short8v*)(bbase + (q4+0)*520);
            const short8v bLo0 = *(const short8v*)(bbase + (q4+0)*520 + 8320);
            acc0 = __builtin_amdgcn_mfma_f32_16x16x32_bf16(aHi, bHi0, acc0, 0,0,0);
            acc0 = __builtin_amdgcn_mfma_f32_16x16x32_bf16(aHi, bLo0, acc0, 0,0,0);
            acc0 = __builtin_amdgcn_mfma_f32_16x16x32_bf16(aLo, bHi0, acc0, 0,0,0);
            const short8v bHi1 = *(const short8v*)(bbase + (q4+1)*520);
            const short8v bLo1 = *(const short8v*)(bbase + (q4+1)*520 + 8320);
            acc1 = __builtin_amdgcn_mfma_f32_16x16x32_bf16(aHi, bHi1, acc1, 0,0,0);
            acc1 = __builtin_amdgcn_mfma_f32_16x16x32_bf16(aHi, bLo1, acc1, 0,0,0);
            acc1 = __builtin_amdgcn_mfma_f32_16x16x32_bf16(aLo, bHi1, acc1, 0,0,0);
            const short8v bHi2 = *(const short8v*)(bbase + (q4+2)*520);
            const short8v bLo2 = *(const short8v*)(bbase + (q4+2)*520 + 8320);
            acc2 = __builtin_amdgcn_mfma_f32_16x16x32_bf16(aHi, bHi2, acc2, 0,0,0);
            acc2 = __builtin_amdgcn_mfma_f32_16x16x32_bf16(aHi, bLo2, acc2, 0,0,0);
            acc2 = __builtin_amdgcn_mfma_f32_16x16x32_bf16(aLo, bHi2, acc2, 0,0,0);
            const short8v bHi3 = *(const short8v*)(bbase + (q4+3)*520);
            const short8v bLo3 = *(const short8v*)(bbase + (q4+3)*520 + 8320);
            acc3 = __builtin_amdgcn_mfma_f32_16x16x32_bf16(aHi, bHi3, acc3, 0,0,0);
            acc3 = __builtin_amdgcn_mfma_f32_16x16x32_bf16(aHi, bLo3, acc3, 0,0,0);
            acc3 = __builtin_amdgcn_mfma_f32_16x16x32_bf16(aLo, bHi3, acc3, 0,0,0);
        }
        __syncthreads();               // all waves done reading buf cur
        if (more) {
            CVT_WRITE(cur ^ 1, g0, g1, g2, g3)
            __syncthreads();           // writes visible for next consume
        }
    }
#undef CVT_WRITE

    // C/D layout (m89-verified): col = lane&15, row(batch) = (lane>>4)*4 + r
    const int colq = colbase + q4*16 + (lane & 15);
    const int brow = bt*16 + (lane >> 4)*4;
#define WB(ACC, I) { \
    _Pragma("unroll") \
    for (int r = 0; r < 4; ++r) \
        Mp[(size_t)(brow + r)*NCOL + colq + (I)*16] = ACC[r]; }
    WB(acc0, 0) WB(acc1, 1) WB(acc2, 2) WB(acc3, 3)
#undef WB
}

// K3: out[j,d] = sum_i exp(-sum_f |M[i,d,f]-M[j,d,f]|) - 1.  (single M)
__global__ __launch_bounds__(256) void k3_pairs(
    const float* __restrict__ Mp, float* __restrict__ outS)
{
    extern __shared__ float sM[];
    const int tid = threadIdx.x;
    const int dd0 = blockIdx.x * 32;
    for (int idx = tid; idx < 32*32*16; idx += 256) {
        const int i = idx >> 9, rem = idx & 511, d = rem >> 4, f = rem & 15;
        sM[(i*32 + d)*17 + f] = Mp[(size_t)i*NCOL + (size_t)dd0*16 + rem];
    }
    __syncthreads();
    const int j = tid >> 3;
    for (int q = 0; q < 4; ++q) {
        const int d = (tid & 7) + q*8;
        float mj[16];
        const float* pj = sM + (j*32 + d)*17;
        #pragma unroll
        for (int f = 0; f < 16; ++f) mj[f] = pj[f];
        float acc = 0.f;
        for (int i = 0; i < 32; ++i) {
            const float* pi = sM + (i*32 + d)*17;
            float dist = 0.f;
            #pragma unroll
            for (int f = 0; f < 16; ++f) dist += fabsf(pi[f] - mj[f]);
            acc += __expf(-dist);
        }
        outS[(size_t)j*D_OUT + dd0 + d] = acc - 1.0f;
    }
}

// K4: ConvTranspose2d, stride==kernel -> no overlap.
__global__ __launch_bounds__(256) void k4_deconv(
    const float* __restrict__ outS, const float* __restrict__ wd,
    float* __restrict__ out)
{
    __shared__ float sO[32*256];
    __shared__ float sWd[32*16];
    const int b   = blockIdx.x >> 5;
    const int oc  = blockIdx.x & 31;
    const int tid = threadIdx.x;
    for (int idx = tid; idx < 8192; idx += 256) sO[idx] = outS[(size_t)b*D_OUT + idx];
    for (int idx = tid; idx < 512; idx += 256) {
        const int ic = idx >> 4, r = idx & 15;
        sWd[idx] = wd[((ic*32 + oc) << 4) + r];
    }
    __syncthreads();
    float* ob = out + (size_t)b*BSTRIDE + (size_t)(128 + oc)*4096;
    for (int s = 0; s < 16; ++s) {
        const int p  = tid + (s << 8);
        const int i  = p >> 6, jc = p & 63;
        const int si = i >> 2, ki = i & 3, sj = jc >> 2, kj = jc & 3;
        float acc = 0.f;
        #pragma unroll
        for (int ic = 0; ic < 32; ++ic)
            acc += sO[ic*256 + si*16 + sj] * sWd[ic*16 + ki*4 + kj];
        ob[p] = acc;
    }
}

extern "C" void kernel_launch(void* const* d_in, const int* in_sizes, int n_in,
                              void* d_out, int out_size, void* d_ws, size_t ws_size,
                              hipStream_t stream) {
    const float* x  = (const float*)d_in[0];
    const float* wc = (const float*)d_in[1];
    const float* Tm = (const float*)d_in[2];
    const float* wd = (const float*)d_in[3];
    float* out  = (float*)d_out;
    ushort* Af  = (ushort*)d_ws;                       // 96 KB @ 0
    float* Mp   = (float*)((char*)d_ws + (1 << 20));   // 16.8 MB @ 1 MB
    float* outS = (float*)((char*)d_ws + (72 << 20));  // 1 MB @ 72 MB

    k1_conv_copy<<<NB*TSP, 256, 0, stream>>>(x, wc, out, Af);                   // 512 blocks
    k2_gemm    <<<NCOL/256, 512, 0, stream>>>(Af, Tm, Mp);                      // 512 blocks
    k3_pairs   <<<D_OUT/32, 256, 32*32*17*sizeof(float), stream>>>(Mp, outS);   // 256 blocks
    k4_deconv  <<<NB*OUTF, 256, 0, stream>>>(outS, wd, out);                    // 1024 blocks
}